// Round 6
// baseline (1986.699 us; speedup 1.0000x reference)
//
#include <hip/hip_runtime.h>

#define K_DIM 4096
#define N_DIM 11008
#define M_DIM 8192
#define NT 64  // K / 64

typedef _Float16 f16;
typedef f16 f16x4 __attribute__((ext_vector_type(4)));
typedef f16 f16x8 __attribute__((ext_vector_type(8)));
typedef float f32x4 __attribute__((ext_vector_type(4)));

typedef __attribute__((address_space(1))) unsigned int gu32;
typedef __attribute__((address_space(3))) unsigned int lu32;

__device__ __forceinline__ void g2l16(const void* gp, void* lp) {
    __builtin_amdgcn_global_load_lds((gu32*)gp, (lu32*)lp, 16, 0, 0);
}

// ---------------------------------------------------------------------------
// Prepass 1: W int32 -> f16 (int8 values are exact in f16)
// ---------------------------------------------------------------------------
__global__ __launch_bounds__(256) void convw_kernel(const int* __restrict__ Wq,
                                                    f16* __restrict__ Wh) {
    const size_t n4 = (size_t)N_DIM * K_DIM / 4;
    const size_t stride = (size_t)gridDim.x * 256;
    const int4* src = (const int4*)Wq;
    f16x4* dst = (f16x4*)Wh;
    for (size_t i = (size_t)blockIdx.x * 256 + threadIdx.x; i < n4; i += stride) {
        int4 a = src[i];
        f16x4 o = {(f16)a.x, (f16)a.y, (f16)a.z, (f16)a.w};
        dst[i] = o;
    }
}

// ---------------------------------------------------------------------------
// Prepass 2: X f32 -> f16 + rowsum of converted values
// ---------------------------------------------------------------------------
__global__ __launch_bounds__(256) void convx_kernel(const float* __restrict__ X,
                                                    f16* __restrict__ Xh,
                                                    float* __restrict__ rs) {
    const int row = blockIdx.x;
    const int t = threadIdx.x;
    const float4* xr = (const float4*)(X + (size_t)row * K_DIM);
    f16x4* xo = (f16x4*)(Xh + (size_t)row * K_DIM);
    float s = 0.f;
#pragma unroll
    for (int j = 0; j < 4; ++j) {
        float4 v = xr[t + 256 * j];
        f16x4 h = {(f16)v.x, (f16)v.y, (f16)v.z, (f16)v.w};
        xo[t + 256 * j] = h;
        s += (float)h[0] + (float)h[1] + (float)h[2] + (float)h[3];
    }
#pragma unroll
    for (int off = 32; off > 0; off >>= 1) s += __shfl_down(s, off);
    __shared__ float part[4];
    if ((t & 63) == 0) part[t >> 6] = s;
    __syncthreads();
    if (t == 0) rs[row] = part[0] + part[1] + part[2] + part[3];
}

// ---------------------------------------------------------------------------
// GEMM: 256x256 tile, BK=64, 8 waves (2Mx4N). R5/R6: B BYPASSES LDS.
// (R6 = identical resubmit of R5: the R5 round died to a container-infra
// failure with no measurement; source audit found no OOB and a consistent
// vmcnt/barrier ledger, so the experiment is re-run unchanged.)
//
// B fragments (16 B/lane, row-contiguous) load straight from global into the
// already-double-buffered b01/b23 register sets; the Wh panel (2 MB) is
// L2-resident (m-fastest dispatch shares it across consecutive blocks) and
// the 32 KB/tile B slice fits L1. This removes 64 KB ds_reads + 32 KB LDS
// stage-writes per tile (-37% LDS traffic); LDS (A only) = 2 x 32 KB.
//
// Shifted 2-compartment schedule (MFMAs consume prev-compartment fragments):
//  C0(T): MFMA Q0(aL x b01) + Q1(aL x b23) || ds_read aH(T) from cur ||
//         issue B(T+1) global->reg (8)
//         end: vmcnt(8)  [A(T+1) landed; leaves B(T+1) in flight]
//              lgkmcnt(0), barrier
//  C1(T): MFMA Q2(aH x b23) + Q3(aH x b01) || ds_read aL(T+1) from cur^1 ||
//         stage A(T+2) -> cur (4 chunks, region dead after C0(T))
//         end: vmcnt(4)  [B(T+1) in regs; leaves A(T+2) in flight]
//              lgkmcnt(0), barrier
// Outstanding-load ledger (steady state): C0-end = A(T+1)[4]+B(T+1)[8]
// -> vmcnt(8) drains A(T+1); C1-end = B(T+1)[8]+A(T+2)[4] -> vmcnt(4)
// drains B(T+1). lgkm0 BEFORE each barrier = cross-wave WAR safety.
// ---------------------------------------------------------------------------
__global__ __launch_bounds__(512, 2)
void qlin_gemm(const f16* __restrict__ Xh, const f16* __restrict__ Wh,
               const float* __restrict__ scale, const float* __restrict__ zp,
               const float* __restrict__ bias, const float* __restrict__ rowsum,
               float* __restrict__ out) {
    extern __shared__ __align__(16) char smem[];

    const int t = threadIdx.x;
    const int l = t & 63;
    const int w = t >> 6;
    const int wm = w >> 2;  // 0..1 -> rows wm*128
    const int wn = w & 3;   // 0..3 -> cols wn*64
    const int q = l >> 4;
    const int ln = l & 15;

    const int m0 = blockIdx.x * 256;  // m-fastest dispatch (R1 win)
    const int n0 = blockIdx.y * 256;

    // A staging: thread t stages local row t>>3 of a 64-row chunk, slot t&7
    const int srow = t >> 3;
    const int sslot = (t & 7) ^ (srow & 7);
    const char* xbase = (const char*)Xh + ((size_t)(m0 + srow) << 13) + (sslot << 4);
    char* ldst = smem + t * 16;

#define STG_A4(p, T)                                                           \
    g2l16(xbase + ((size_t)(T) << 7), ldst + (p)*32768);                       \
    g2l16(xbase + (1ull << 19) + ((size_t)(T) << 7), ldst + (p)*32768 + 8192); \
    g2l16(xbase + (2ull << 19) + ((size_t)(T) << 7), ldst + (p)*32768 + 16384);\
    g2l16(xbase + (3ull << 19) + ((size_t)(T) << 7), ldst + (p)*32768 + 24576)
#define SB __builtin_amdgcn_sched_barrier(0)
#define BAR __builtin_amdgcn_s_barrier()
#define LGKM0 asm volatile("s_waitcnt lgkmcnt(0)" ::: "memory")
#define VMC12 asm volatile("s_waitcnt vmcnt(12)" ::: "memory")
#define VMC8 asm volatile("s_waitcnt vmcnt(8)" ::: "memory")
#define VMC4 asm volatile("s_waitcnt vmcnt(4)" ::: "memory")
#define VMC0 asm volatile("s_waitcnt vmcnt(0)" ::: "memory")

    // A ds_read lane offsets: row = wm*128 + frag*16 + ln, slot (q+kk*4)^(ln&7)
    const int xs = ln & 7;
    int offA[2];
    offA[0] = (wm * 128 + ln) * 128 + ((q ^ xs) << 4);
    offA[1] = (wm * 128 + ln) * 128 + (((q + 4) ^ xs) << 4);

    // B per-lane global base: col n = n0 + wn*64 + nf*16 + ln; k-byte = q*16
    const char* wc[4];
#pragma unroll
    for (int nf = 0; nf < 4; ++nf)
        wc[nf] = (const char*)Wh + ((size_t)(n0 + wn * 64 + nf * 16 + ln) << 13) + (q << 4);

    f32x4 acc[8][4] = {};
    f16x8 aL[4][2], aH[4][2];
    f16x8 b01A[2][2], b23A[2][2], b01B[2][2], b23B[2][2];

#define RD_AL(P)                                                               \
    _Pragma("unroll") for (int kk = 0; kk < 2; ++kk)                           \
    _Pragma("unroll") for (int i = 0; i < 4; ++i)                              \
        aL[i][kk] = *(const f16x8*)(smem + (P)*32768 + offA[kk] + i * 2048)
#define RD_AH(P)                                                               \
    _Pragma("unroll") for (int kk = 0; kk < 2; ++kk)                           \
    _Pragma("unroll") for (int i = 0; i < 4; ++i)                              \
        aH[i][kk] = *(const f16x8*)(smem + (P)*32768 + offA[kk] + (4 + i) * 2048)
// B global->reg: tile T, set S: b01S[j][kk] = W[n(nf=j)][k: T*64 + kk*32 + 8q..]
#define LD_B(S, T)                                                             \
    _Pragma("unroll") for (int kk = 0; kk < 2; ++kk) {                         \
        _Pragma("unroll") for (int j = 0; j < 2; ++j) {                        \
            b01##S[j][kk] = *(const f16x8*)(wc[j] + ((T) << 7) + (kk << 6));   \
            b23##S[j][kk] = *(const f16x8*)(wc[2 + j] + ((T) << 7) + (kk << 6));\
        }                                                                      \
    }
#define MFMA_BLK(I0, J0, ASET, BSET)                                           \
    _Pragma("unroll") for (int kk = 0; kk < 2; ++kk)                           \
    _Pragma("unroll") for (int i = 0; i < 4; ++i)                              \
    _Pragma("unroll") for (int j = 0; j < 2; ++j)                              \
        acc[(I0) + i][(J0) + j] = __builtin_amdgcn_mfma_f32_16x16x32_f16(      \
            ASET[i][kk], BSET[j][kk], acc[(I0) + i][(J0) + j], 0, 0, 0)

    // ---- prologue: A(0)->buf0 [4], B(0)->regs [8], A(1)->buf1 [4] ----
    STG_A4(0, 0);
    LD_B(A, 0);
    STG_A4(1, 1);
    VMC12;  // A(0) landed (leaves B(0)+A(1) in flight)
    SB; BAR; SB;
    // pre-compartment: read aL(0); drain B(0) into regs
    RD_AL(0);
    VMC4;   // B(0) in regs (leaves A(1))
    LGKM0; SB; BAR; SB;

#define BODY(T, CUR, BS, BD)                                                   \
    /* C0: MFMA Q0,Q1 || ds_read aH(T) || issue B(T+1)->other set */           \
    RD_AH(CUR);                                                                \
    MFMA_BLK(0, 0, aL, b01##BS);                                               \
    MFMA_BLK(0, 2, aL, b23##BS);                                               \
    LD_B(BD, (T) + 1);                                                         \
    VMC8; LGKM0; SB; BAR; SB;                                                  \
    /* C1: MFMA Q2,Q3 || ds_read aL(T+1) from buf^1 || stage A(T+2)->cur */    \
    RD_AL((CUR) ^ 1);                                                          \
    MFMA_BLK(4, 2, aH, b23##BS);                                               \
    MFMA_BLK(4, 0, aH, b01##BS);                                               \
    STG_A4(CUR, (T) + 2);                                                      \
    VMC4; LGKM0; SB; BAR; SB;

    // main loop: tiles 0..61 (B-issue T+1 <= 62, A-stage T+2 <= 63)
#pragma unroll 1
    for (int Tp = 0; Tp < 31; ++Tp) {
        BODY(2 * Tp, 0, A, B);
        BODY(2 * Tp + 1, 1, B, A);
    }
#undef BODY

    // ---- tail: tile 62 (buf0, consume set A) ----
    RD_AH(0);
    MFMA_BLK(0, 0, aL, b01A);
    MFMA_BLK(0, 2, aL, b23A);
    LD_B(B, 63);
    VMC8; LGKM0; SB; BAR; SB;   // A(63) landed (leaves B(63) in flight)
    RD_AL(1);
    MFMA_BLK(4, 2, aH, b23A);
    MFMA_BLK(4, 0, aH, b01A);
    VMC0; LGKM0; SB;            // B(63) in regs, aL(63) read
    // ---- tail: tile 63 (buf1, register-only ordering) ----
    RD_AH(1);
    MFMA_BLK(0, 0, aL, b01B);
    MFMA_BLK(0, 2, aL, b23B);
    LGKM0; SB;
    MFMA_BLK(4, 2, aH, b23B);
    MFMA_BLK(4, 0, aH, b01B);

    // epilogue: y[m,n] = scale[n]*(dot - zp[n]*rowsum[m]) + bias[n]
    float sc[4], zv[4], bv[4];
    int ncol[4];
#pragma unroll
    for (int j = 0; j < 4; ++j) {
        const int n = n0 + wn * 64 + j * 16 + ln;
        ncol[j] = n;
        sc[j] = scale[n];
        zv[j] = zp[n];
        bv[j] = bias[n];
    }
#pragma unroll
    for (int i = 0; i < 8; ++i) {
#pragma unroll
        for (int r = 0; r < 4; ++r) {
            const int m = m0 + wm * 128 + i * 16 + q * 4 + r;
            const float rsm = rowsum[m];
            const size_t rowoff = (size_t)m * N_DIM;
#pragma unroll
            for (int j = 0; j < 4; ++j) {
                out[rowoff + ncol[j]] = sc[j] * (acc[i][j][r] - zv[j] * rsm) + bv[j];
            }
        }
    }
}

extern "C" void kernel_launch(void* const* d_in, const int* in_sizes, int n_in,
                              void* d_out, int out_size, void* d_ws, size_t ws_size,
                              hipStream_t stream) {
    const float* X     = (const float*)d_in[0];
    const int*   Wq    = (const int*)d_in[1];
    const float* scale = (const float*)d_in[2];
    const float* zp    = (const float*)d_in[3];
    const float* bias  = (const float*)d_in[4];
    float* out = (float*)d_out;

    // ws layout: Wh (90,177,536 B) | Xh (67,108,864 B) | rowsum (32 KB)
    f16* Wh = (f16*)d_ws;
    f16* Xh = (f16*)((char*)d_ws + (size_t)N_DIM * K_DIM * 2);
    float* rowsum = (float*)((char*)d_ws + (size_t)N_DIM * K_DIM * 2 + (size_t)M_DIM * K_DIM * 2);

    static bool attr_done = false;
    if (!attr_done) {
        (void)hipFuncSetAttribute((const void*)qlin_gemm,
                                  hipFuncAttributeMaxDynamicSharedMemorySize, 65536);
        attr_done = true;
    }

    convw_kernel<<<4096, 256, 0, stream>>>(Wq, Wh);
    convx_kernel<<<M_DIM, 256, 0, stream>>>(X, Xh, rowsum);

    dim3 grid(M_DIM / 256, N_DIM / 256);  // (32, 43): m-fastest for W stream-once
    qlin_gemm<<<grid, 512, 65536, stream>>>(Xh, Wh, scale, zp, bias, rowsum, out);
}

// Round 7
// 1236.646 us; speedup vs baseline: 1.6065x; 1.6065x over previous
//
#include <hip/hip_runtime.h>

#define K_DIM 4096
#define N_DIM 11008
#define M_DIM 8192
#define NT 128  // K / 32

typedef _Float16 f16;
typedef f16 f16x4 __attribute__((ext_vector_type(4)));
typedef f16 f16x8 __attribute__((ext_vector_type(8)));
typedef float f32x4 __attribute__((ext_vector_type(4)));

typedef __attribute__((address_space(1))) unsigned int gu32;
typedef __attribute__((address_space(3))) unsigned int lu32;

__device__ __forceinline__ void g2l16(const void* gp, void* lp) {
    __builtin_amdgcn_global_load_lds((gu32*)gp, (lu32*)lp, 16, 0, 0);
}

// ---------------------------------------------------------------------------
// Prepass 1: W int32 -> f16 (int8 values are exact in f16)
// ---------------------------------------------------------------------------
__global__ __launch_bounds__(256) void convw_kernel(const int* __restrict__ Wq,
                                                    f16* __restrict__ Wh) {
    const size_t n4 = (size_t)N_DIM * K_DIM / 4;
    const size_t stride = (size_t)gridDim.x * 256;
    const int4* src = (const int4*)Wq;
    f16x4* dst = (f16x4*)Wh;
    for (size_t i = (size_t)blockIdx.x * 256 + threadIdx.x; i < n4; i += stride) {
        int4 a = src[i];
        f16x4 o = {(f16)a.x, (f16)a.y, (f16)a.z, (f16)a.w};
        dst[i] = o;
    }
}

// ---------------------------------------------------------------------------
// Prepass 2: X f32 -> f16 + rowsum of converted values
// ---------------------------------------------------------------------------
__global__ __launch_bounds__(256) void convx_kernel(const float* __restrict__ X,
                                                    f16* __restrict__ Xh,
                                                    float* __restrict__ rs) {
    const int row = blockIdx.x;
    const int t = threadIdx.x;
    const float4* xr = (const float4*)(X + (size_t)row * K_DIM);
    f16x4* xo = (f16x4*)(Xh + (size_t)row * K_DIM);
    float s = 0.f;
#pragma unroll
    for (int j = 0; j < 4; ++j) {
        float4 v = xr[t + 256 * j];
        f16x4 h = {(f16)v.x, (f16)v.y, (f16)v.z, (f16)v.w};
        xo[t + 256 * j] = h;
        s += (float)h[0] + (float)h[1] + (float)h[2] + (float)h[3];
    }
#pragma unroll
    for (int off = 32; off > 0; off >>= 1) s += __shfl_down(s, off);
    __shared__ float part[4];
    if ((t & 63) == 0) part[t >> 6] = s;
    __syncthreads();
    if (t == 0) rs[row] = part[0] + part[1] + part[2] + part[3];
}

// ---------------------------------------------------------------------------
// GEMM (R7): 256x128 tile, BK=32, 256 threads = 4 waves (2Mx2N), per-wave
// 128x64. LDS = 2 bufs x (A 16K | B 8K) = 48 KB -> TWO blocks/CU, i.e. two
// INDEPENDENT barrier groups per CU: one block's vmcnt/lgkm drain+barrier
// stall is hidden by the other block's MFMAs (m114 wave-level overlap).
// R6's B-global-bypass reverted (16-row-scattered loads killed the TA path);
// both A and B go through the verified global_load_lds route.
//
// LDS rows are 64 B = 4 slots of 16 B; phys slot = logical ^ ((row>>1)&3).
// global_load_lds writes linearly, so the swizzle is applied on the GLOBAL
// source: staging thread t (row t>>2, slot t&3) fetches logical slot
// (t&3)^((t>>3)&3). Reads use slot (q ^ ((ln>>1)&3)): per quarter-wave the
// 16 lanes produce 8 distinct 4-bank footprints x 2 lanes = 2-way = free.
//
// 2-compartment shifted schedule (R4-verified, ledger rescaled; chunk=4KB):
//  C0(T): MFMA Q0(aL x b01) + Q1(aL x b23) || ds_read aH(T) from cur ||
//         stage B(T+2)[2] -> cur;  end: vmcnt(2) [drains B(T+1)+A(T+1);
//         leaves B(T+2)], lgkmcnt(0), barrier
//  C1(T): MFMA Q2(aH x b23) + Q3(aH x b01) || ds_read aL/b01/b23(T+1) from
//         cur^1 || stage A(T+2)[4] -> cur;  end: lgkmcnt(0), barrier
// Ledger: entering C0(T) outstanding = B(T+1)[2]+A(T+1)[4] = 6; +B(T+2)[2]
// = 8 at vmcnt(2). lgkm0 BEFORE each barrier = cross-wave WAR safety.
// ---------------------------------------------------------------------------
__global__ __launch_bounds__(256, 2)
void qlin_gemm(const f16* __restrict__ Xh, const f16* __restrict__ Wh,
               const float* __restrict__ scale, const float* __restrict__ zp,
               const float* __restrict__ bias, const float* __restrict__ rowsum,
               float* __restrict__ out) {
    extern __shared__ __align__(16) char smem[];

    const int t = threadIdx.x;
    const int l = t & 63;
    const int w = t >> 6;   // 0..3
    const int wm = w >> 1;  // 0..1 -> rows wm*128
    const int wn = w & 1;   // 0..1 -> cols wn*64
    const int q = l >> 4;
    const int ln = l & 15;

    const int m0 = blockIdx.x * 256;  // m-fastest dispatch (R1 win)
    const int n0 = blockIdx.y * 128;

    // staging: thread t -> row t>>2 of a 64-row chunk, phys slot t&3
    const int srow = t >> 2;
    const int sg = (t & 3) ^ ((t >> 3) & 3);  // pre-swizzled logical slot
    const char* xbase = (const char*)Xh + ((size_t)(m0 + srow) << 13) + (sg << 4);
    const char* wbase = (const char*)Wh + ((size_t)(n0 + srow) << 13) + (sg << 4);
    char* ldst = smem + t * 16;

#define STG_A4(p, T)                                                            \
    g2l16(xbase + ((size_t)(T) << 6), ldst + (p)*24576);                        \
    g2l16(xbase + (1ull << 19) + ((size_t)(T) << 6), ldst + (p)*24576 + 4096);  \
    g2l16(xbase + (2ull << 19) + ((size_t)(T) << 6), ldst + (p)*24576 + 8192);  \
    g2l16(xbase + (3ull << 19) + ((size_t)(T) << 6), ldst + (p)*24576 + 12288)
#define STG_B2(p, T)                                                            \
    g2l16(wbase + ((size_t)(T) << 6), ldst + (p)*24576 + 16384);                \
    g2l16(wbase + (1ull << 19) + ((size_t)(T) << 6), ldst + (p)*24576 + 20480)
#define SB __builtin_amdgcn_sched_barrier(0)
#define BAR __builtin_amdgcn_s_barrier()
#define LGKM0 asm volatile("s_waitcnt lgkmcnt(0)" ::: "memory")
#define VMC6 asm volatile("s_waitcnt vmcnt(6)" ::: "memory")
#define VMC2 asm volatile("s_waitcnt vmcnt(2)" ::: "memory")
#define VMC0 asm volatile("s_waitcnt vmcnt(0)" ::: "memory")

    // ds_read lane offsets: row = base + frag*16 + ln, phys slot q^((ln>>1)&3)
    const int xs2 = (ln >> 1) & 3;
    const int offA = (wm * 128 + ln) * 64 + ((q ^ xs2) << 4);
    const int offB = 16384 + (wn * 64 + ln) * 64 + ((q ^ xs2) << 4);

    f32x4 acc[8][4] = {};
    f16x8 aL[4], aH[4];
    f16x8 b01A[2], b23A[2], b01B[2], b23B[2];

#define RD_AL(P)                                                               \
    _Pragma("unroll") for (int i = 0; i < 4; ++i)                              \
        aL[i] = *(const f16x8*)(smem + (P)*24576 + offA + i * 1024)
#define RD_AH(P)                                                               \
    _Pragma("unroll") for (int i = 0; i < 4; ++i)                              \
        aH[i] = *(const f16x8*)(smem + (P)*24576 + offA + (4 + i) * 1024)
#define RD_B01(P, D)                                                           \
    _Pragma("unroll") for (int j = 0; j < 2; ++j)                              \
        D[j] = *(const f16x8*)(smem + (P)*24576 + offB + j * 1024)
#define RD_B23(P, D)                                                           \
    _Pragma("unroll") for (int j = 0; j < 2; ++j)                              \
        D[j] = *(const f16x8*)(smem + (P)*24576 + offB + (2 + j) * 1024)
#define MFMA_BLK(I0, J0, ASET, BSET)                                           \
    _Pragma("unroll") for (int i = 0; i < 4; ++i)                              \
    _Pragma("unroll") for (int j = 0; j < 2; ++j)                              \
        acc[(I0) + i][(J0) + j] = __builtin_amdgcn_mfma_f32_16x16x32_f16(      \
            ASET[i], BSET[j], acc[(I0) + i][(J0) + j], 0, 0, 0)

    // ---- prologue: B(0),A(0)->buf0; B(1),A(1)->buf1; vmcnt(6): T0 landed ----
    STG_B2(0, 0); STG_A4(0, 0);
    STG_B2(1, 1); STG_A4(1, 1);
    VMC6; SB; BAR; SB;
    // pre-compartment (== C1 of virtual tile -1): read T0 frags
    RD_AL(0); RD_B01(0, b01A); RD_B23(0, b23A);
    LGKM0; SB; BAR; SB;

#define BODY(T, CUR, BS, BD)                                                   \
    /* C0: MFMA Q0,Q1 || ds_read aH(T) || stage B(T+2)->cur */                 \
    RD_AH(CUR);                                                                \
    MFMA_BLK(0, 0, aL, b01##BS);                                               \
    MFMA_BLK(0, 2, aL, b23##BS);                                               \
    STG_B2(CUR, (T) + 2);                                                      \
    VMC2; LGKM0; SB; BAR; SB;                                                  \
    /* C1: MFMA Q2,Q3 || ds_read aL/b01/b23(T+1) from cur^1 || stage A(T+2) */ \
    RD_AL((CUR) ^ 1); RD_B01((CUR) ^ 1, b01##BD); RD_B23((CUR) ^ 1, b23##BD);  \
    MFMA_BLK(4, 2, aH, b23##BS);                                               \
    MFMA_BLK(4, 0, aH, b01##BS);                                               \
    STG_A4(CUR, (T) + 2);                                                      \
    LGKM0; SB; BAR; SB;

    // main loop: tiles 0..125 (stage target T+2 <= 127 always valid)
#pragma unroll 1
    for (int Tp = 0; Tp < 63; ++Tp) {
        BODY(2 * Tp, 0, A, B);
        BODY(2 * Tp + 1, 1, B, A);
    }
#undef BODY

    // ---- tail: tile 126 (buf0, set A; no more stages) ----
    RD_AH(0);
    MFMA_BLK(0, 0, aL, b01A);
    MFMA_BLK(0, 2, aL, b23A);
    VMC0; LGKM0; SB; BAR; SB;   // B(127)+A(127) landed
    RD_AL(1); RD_B01(1, b01B); RD_B23(1, b23B);
    MFMA_BLK(4, 2, aH, b23A);
    MFMA_BLK(4, 0, aH, b01A);
    LGKM0; SB;
    // ---- tail: tile 127 (buf1, set B; same-thread ordering only) ----
    RD_AH(1);
    MFMA_BLK(0, 0, aL, b01B);
    MFMA_BLK(0, 2, aL, b23B);
    LGKM0; SB;
    MFMA_BLK(4, 2, aH, b23B);
    MFMA_BLK(4, 0, aH, b01B);

    // epilogue: y[m,n] = scale[n]*(dot - zp[n]*rowsum[m]) + bias[n]
    float sc[4], zv[4], bv[4];
    int ncol[4];
#pragma unroll
    for (int j = 0; j < 4; ++j) {
        const int n = n0 + wn * 64 + j * 16 + ln;
        ncol[j] = n;
        sc[j] = scale[n];
        zv[j] = zp[n];
        bv[j] = bias[n];
    }
#pragma unroll
    for (int i = 0; i < 8; ++i) {
#pragma unroll
        for (int r = 0; r < 4; ++r) {
            const int m = m0 + wm * 128 + i * 16 + q * 4 + r;
            const float rsm = rowsum[m];
            const size_t rowoff = (size_t)m * N_DIM;
#pragma unroll
            for (int j = 0; j < 4; ++j) {
                out[rowoff + ncol[j]] = sc[j] * (acc[i][j][r] - zv[j] * rsm) + bv[j];
            }
        }
    }
}

extern "C" void kernel_launch(void* const* d_in, const int* in_sizes, int n_in,
                              void* d_out, int out_size, void* d_ws, size_t ws_size,
                              hipStream_t stream) {
    const float* X     = (const float*)d_in[0];
    const int*   Wq    = (const int*)d_in[1];
    const float* scale = (const float*)d_in[2];
    const float* zp    = (const float*)d_in[3];
    const float* bias  = (const float*)d_in[4];
    float* out = (float*)d_out;

    // ws layout: Wh (90,177,536 B) | Xh (67,108,864 B) | rowsum (32 KB)
    f16* Wh = (f16*)d_ws;
    f16* Xh = (f16*)((char*)d_ws + (size_t)N_DIM * K_DIM * 2);
    float* rowsum = (float*)((char*)d_ws + (size_t)N_DIM * K_DIM * 2 + (size_t)M_DIM * K_DIM * 2);

    static bool attr_done = false;
    if (!attr_done) {
        (void)hipFuncSetAttribute((const void*)qlin_gemm,
                                  hipFuncAttributeMaxDynamicSharedMemorySize, 49152);
        attr_done = true;
    }

    convw_kernel<<<4096, 256, 0, stream>>>(Wq, Wh);
    convx_kernel<<<M_DIM, 256, 0, stream>>>(X, Xh, rowsum);

    dim3 grid(M_DIM / 256, N_DIM / 128);  // (32, 86): m-fastest for W stream-once
    qlin_gemm<<<grid, 256, 49152, stream>>>(Xh, Wh, scale, zp, bias, rowsum, out);
}